// Round 4
// baseline (29.651 us; speedup 1.0000x reference)
//
#include <hip/hip_runtime.h>

// GSA loss: pred [B=2,1,64,64] fp32, token [B,4096,4096] fp32 -> scalar fp32.
// loss = 2 - s_fa/s_f - s_bb/s_b with
//   T   = sum t_ij
//   s_f = sum p_i t_ij        (row-weighted)
//   s_c = sum t_ij p_j        (col-weighted; token NOT symmetric)
//   s_fa= sum p_i t_ij p_j
//   s_b = T - s_f
//   s_bb= T - s_f - s_c + s_fa
//
// R2: killed the same-address fp64 atomics (117.9 -> 29.6 us).
// R3: startup overlap — issue the 16 token loads BEFORE pred LDS staging so
// the HBM long-pole starts at cycle ~0 instead of after pred-load + barrier
// (all 2048 blocks are co-resident: one burst, startup is on the critical
// path). Two independent accumulator chains. Stage-2 loads vectorized.

#define HW   4096
#define HW4  1024   // HW / 4
#define NBLK 2048

struct alignas(32) D4 { double t, f, c, fa; };

__global__ __launch_bounds__(256, 4) void gsa_partial(
    const float* __restrict__ pred,
    const float* __restrict__ token,
    D4* __restrict__ part)           // part[NBLK]
{
    __shared__ float4 pj_lds[HW4];   // 16 KB: pred row for this batch
    __shared__ double sm[4][4];

    const float4* __restrict__ tok4  = (const float4*)token;
    const float4* __restrict__ pred4 = (const float4*)pred;

    const int bid  = blockIdx.x;     // 0..2047
    const int b    = bid >> 10;      // rows 4*bid..4*bid+3 all in batch b
    const int wave = threadIdx.x >> 6;
    const int lane = threadIdx.x & 63;
    const int row  = bid * 4 + wave; // global row in [0, B*HW)

    const float4* __restrict__ rowp = tok4 + (size_t)row * HW4;

    // 1) issue ALL token loads first — 16 KB/wave in flight immediately
    float4 t[16];
#pragma unroll
    for (int u = 0; u < 16; ++u)
        t[u] = rowp[u * 64 + lane];

    // 2) pred staging overlaps the token loads' latency
    for (int k = threadIdx.x; k < HW4; k += 256)
        pj_lds[k] = pred4[b * HW4 + k];
    const float pi = pred[row];      // wave-uniform load

    __syncthreads();                 // drains vmcnt: token loads done too

    // 3) compute, two independent chains
    float s0 = 0.f, s1 = 0.f, d0 = 0.f, d1 = 0.f;
#pragma unroll
    for (int u = 0; u < 16; u += 2) {
        float4 pa = pj_lds[u * 64 + lane];
        float4 pb = pj_lds[(u + 1) * 64 + lane];
        s0 += t[u].x + t[u].y + t[u].z + t[u].w;
        d0 += t[u].x * pa.x + t[u].y * pa.y + t[u].z * pa.z + t[u].w * pa.w;
        s1 += t[u+1].x + t[u+1].y + t[u+1].z + t[u+1].w;
        d1 += t[u+1].x * pb.x + t[u+1].y * pb.y + t[u+1].z * pb.z + t[u+1].w * pb.w;
    }
    float s = s0 + s1, d = d0 + d1;

    float tT  = s;
    float tF  = pi * s;
    float tC  = d;
    float tFA = pi * d;

    for (int off = 32; off > 0; off >>= 1) {
        tT  += __shfl_down(tT,  off);
        tF  += __shfl_down(tF,  off);
        tC  += __shfl_down(tC,  off);
        tFA += __shfl_down(tFA, off);
    }

    if (lane == 0) {
        sm[wave][0] = (double)tT;
        sm[wave][1] = (double)tF;
        sm[wave][2] = (double)tC;
        sm[wave][3] = (double)tFA;
    }
    __syncthreads();

    if (threadIdx.x == 0) {
        D4 p;
        p.t  = sm[0][0] + sm[1][0] + sm[2][0] + sm[3][0];
        p.f  = sm[0][1] + sm[1][1] + sm[2][1] + sm[3][1];
        p.c  = sm[0][2] + sm[1][2] + sm[2][2] + sm[3][2];
        p.fa = sm[0][3] + sm[1][3] + sm[2][3] + sm[3][3];
        part[bid] = p;               // plain store — no atomics
    }
}

__global__ __launch_bounds__(256) void gsa_final(
    const D4* __restrict__ part, float* __restrict__ out)
{
    const double2* __restrict__ p2 = (const double2*)part;  // [NBLK*2]

    double aT = 0.0, aF = 0.0, aC = 0.0, aFA = 0.0;
    // each thread: 8 D4s = 16 double2 loads, all independent
    for (int k = threadIdx.x; k < NBLK; k += 256) {
        double2 lo = p2[k * 2 + 0];   // {t, f}
        double2 hi = p2[k * 2 + 1];   // {c, fa}
        aT += lo.x; aF += lo.y; aC += hi.x; aFA += hi.y;
    }

    for (int off = 32; off > 0; off >>= 1) {
        aT  += __shfl_down(aT,  off);
        aF  += __shfl_down(aF,  off);
        aC  += __shfl_down(aC,  off);
        aFA += __shfl_down(aFA, off);
    }

    __shared__ double sm[4][4];
    const int wave = threadIdx.x >> 6;
    const int lane = threadIdx.x & 63;
    if (lane == 0) {
        sm[wave][0] = aT; sm[wave][1] = aF;
        sm[wave][2] = aC; sm[wave][3] = aFA;
    }
    __syncthreads();

    if (threadIdx.x == 0) {
        double T   = sm[0][0] + sm[1][0] + sm[2][0] + sm[3][0];
        double sf  = sm[0][1] + sm[1][1] + sm[2][1] + sm[3][1];
        double sc  = sm[0][2] + sm[1][2] + sm[2][2] + sm[3][2];
        double sfa = sm[0][3] + sm[1][3] + sm[2][3] + sm[3][3];
        double sb  = T - sf;
        double sbb = T - sf - sc + sfa;
        out[0] = (float)(2.0 - sfa / sf - sbb / sb);
    }
}

extern "C" void kernel_launch(void* const* d_in, const int* in_sizes, int n_in,
                              void* d_out, int out_size, void* d_ws, size_t ws_size,
                              hipStream_t stream)
{
    const float* pred  = (const float*)d_in[0];
    const float* token = (const float*)d_in[1];
    float* out  = (float*)d_out;
    D4*    part = (D4*)d_ws;         // 2048 * 32 B = 64 KB scratch

    // stage 1: one token row per wave, per-block partials (every part[] slot
    // is overwritten every call — no memset needed)
    gsa_partial<<<NBLK, 256, 0, stream>>>(pred, token, part);
    // stage 2: deterministic fixed-order reduction + scalar epilogue
    gsa_final<<<1, 256, 0, stream>>>(part, out);
}